// Round 6
// baseline (445.809 us; speedup 1.0000x reference)
//
#include <hip/hip_runtime.h>

typedef unsigned short u16;
typedef unsigned int u32;
typedef __attribute__((ext_vector_type(8))) _Float16 half8;
typedef __attribute__((ext_vector_type(4))) float floatx4;
typedef __attribute__((ext_vector_type(4))) u32 uintx4;

// ---------------- helpers ----------------
__device__ __forceinline__ u16 f2h(float f) {
  union { _Float16 h; u16 u; } v; v.h = (_Float16)f; return v.u;
}
__device__ __forceinline__ float h2f(u16 u) {
  union { u16 u; _Float16 h; } v; v.u = u; return (float)v.h;
}

typedef __attribute__((address_space(1))) const void* as1cv;
typedef __attribute__((address_space(3))) void* as3v;
__device__ __forceinline__ void gload16(const void* g, void* l) {
  __builtin_amdgcn_global_load_lds((as1cv)g, (as3v)l, 16, 0, 0);
}

// ---------------- ws layout (bytes) ----------------
static constexpr size_t OFF_XP   = 0;         // [32][36][36][256] f16
static constexpr size_t OFF_YMID = 21233664;  // [32][34][34][256] f16
static constexpr size_t OFF_OFFB = 40173568;  // [32768][64] f32
static constexpr size_t OFF_WB1  = 48562176;  // [256][2304] f16 (swizzled)
static constexpr size_t OFF_WBO  = 49741824;  // [64][2304] f16 (swizzled)
static constexpr size_t OFF_WB3  = 50036736;  // [256][6400] f16 (swizzled)
static constexpr size_t OFF_WB2  = 53313536;  // [256][2304] f16 (swizzled)
static constexpr size_t OFF_BNP  = 54493184;  // [6][256] f32

// ---------------- zero fill ----------------
__global__ __launch_bounds__(256) void zero_kernel(uintx4* __restrict__ p, int n) {
  int i = blockIdx.x * 256 + threadIdx.x;
  if (i < n) { uintx4 z = {0u, 0u, 0u, 0u}; p[i] = z; }
}

// ---------------- pack weights (XOR-swizzled) + bn params ----------------
// packed[p][kt*64 + slot*8 + j] = orig channel-group (slot ^ (p&7)) of
// 64-ch window (kt&3), tap (kt>>2). Readers XOR slot with (row&7).
__global__ __launch_bounds__(256) void prep_kernel(
    const float* __restrict__ w1, const float* __restrict__ woff,
    const float* __restrict__ w3, const float* __restrict__ w2,
    const float* __restrict__ g1, const float* __restrict__ b1,
    const float* __restrict__ m1, const float* __restrict__ v1,
    const float* __restrict__ g3, const float* __restrict__ b3,
    const float* __restrict__ m3, const float* __restrict__ v3,
    const float* __restrict__ g2, const float* __restrict__ b2,
    const float* __restrict__ m2, const float* __restrict__ v2,
    u16* __restrict__ wB1, u16* __restrict__ wBo,
    u16* __restrict__ wB3, u16* __restrict__ wB2,
    float* __restrict__ bnp)
{
  int i = blockIdx.x * 256 + threadIdx.x;
  if (i < 589824) {                    // wB1 [256][2304]
    int p = i / 2304, kcol = i - p * 2304;
    int kt = kcol >> 6, slot = (kcol >> 3) & 7, j = kcol & 7;
    int c = ((kt & 3) << 6) + ((slot ^ (p & 7)) << 3) + j;
    wB1[i] = f2h(w1[(p * 256 + c) * 9 + (kt >> 2)]);
    return;
  }
  i -= 589824;
  if (i < 147456) {                    // wBo [64][2304] (rows >= 50 zero)
    int p = i / 2304, kcol = i - p * 2304;
    int kt = kcol >> 6, slot = (kcol >> 3) & 7, j = kcol & 7;
    int c = ((kt & 3) << 6) + ((slot ^ (p & 7)) << 3) + j;
    wBo[i] = (p < 50) ? f2h(woff[(p * 256 + c) * 9 + (kt >> 2)]) : (u16)0;
    return;
  }
  i -= 147456;
  if (i < 1638400) {                   // wB3 [256][6400]
    int p = i / 6400, kcol = i - p * 6400;
    int kt = kcol >> 6, slot = (kcol >> 3) & 7, j = kcol & 7;
    int c = ((kt & 3) << 6) + ((slot ^ (p & 7)) << 3) + j;
    wB3[i] = f2h(w3[(p * 256 + c) * 25 + (kt >> 2)]);
    return;
  }
  i -= 1638400;
  if (i < 589824) {                    // wB2
    int p = i / 2304, kcol = i - p * 2304;
    int kt = kcol >> 6, slot = (kcol >> 3) & 7, j = kcol & 7;
    int c = ((kt & 3) << 6) + ((slot ^ (p & 7)) << 3) + j;
    wB2[i] = f2h(w2[(p * 256 + c) * 9 + (kt >> 2)]);
    return;
  }
  i -= 589824;
  if (i < 1536) {                      // bn params
    int grp = i >> 8, n = i & 255;
    const float* g  = (grp < 2) ? g1 : (grp < 4) ? g3 : g2;
    const float* bb = (grp < 2) ? b1 : (grp < 4) ? b3 : b2;
    const float* mm = (grp < 2) ? m1 : (grp < 4) ? m3 : m2;
    const float* vv = (grp < 2) ? v1 : (grp < 4) ? v3 : v2;
    float sc = g[n] / sqrtf(vv[n] + 1e-5f);
    bnp[i] = (grp & 1) ? (bb[n] - mm[n] * sc) : sc;
  }
}

// ---------------- pack x: NCHW f32 -> NHWC f16 border-2 ----------------
__global__ __launch_bounds__(256) void pack_x_kernel(const float* __restrict__ x,
                                                     u16* __restrict__ xp)
{
  __shared__ float trans[256][33];
  int b = blockIdx.x >> 5, y = blockIdx.x & 31;
  int t = threadIdx.x;
  int xi = t & 31, ch = t >> 5;
  const float* src = x + (b * 256 * 1024) + y * 32 + xi;
#pragma unroll 4
  for (int c8 = 0; c8 < 32; ++c8) {
    int c = c8 * 8 + ch;
    trans[c][xi] = src[c * 1024];
  }
  __syncthreads();
  u16* dstrow = xp + ((b * 36 + y + 2) * 36 + 2) * 256 + t;
#pragma unroll 4
  for (int xx = 0; xx < 32; ++xx)
    dstrow[xx * 256] = f2h(trans[t][xx]);
}

// ---------------- implicit-GEMM 3x3 conv ----------------
// XCD-aware swizzle: (phys&7)*per + (phys>>3) -> contiguous m-range per XCD.
template <int BN, int NBX, int WPAD, int EPI>
__global__ __launch_bounds__(256) void conv3x3_kernel(
    const u16* __restrict__ img, const u16* __restrict__ wB,
    const float* __restrict__ p0, const float* __restrict__ p1,
    const float* __restrict__ xorig, void* __restrict__ dst)
{
  constexpr int K = 2304;
  constexpr int NI = BN / 32;
  constexpr int BQ = BN / 32;
  constexpr int BRW = BN / 4;
  constexpr int BRD = (WPAD - 34) / 2;
  constexpr int PER = (NBX * 256) / 8;

  const int t = threadIdx.x;
  const int wave = t >> 6, lane = t & 63;
  const int lin = blockIdx.y * NBX + blockIdx.x;
  const int swz = (lin & 7) * PER + (lin >> 3);
  const int mBlk = (swz / NBX) * 128;
  const int nBlk = (swz % NBX) * BN;
  const int wm = wave >> 1, wn = wave & 1;

  __shared__ u16 Alds[128 * 64];
  __shared__ u16 Blds[BN * 64];

  int arow[4];
  {
    const int r0 = wave * 32 + (lane >> 3);
    const int chunk = (lane & 7) ^ (lane >> 3);   // XOR-swizzled source chunk
#pragma unroll
    for (int q = 0; q < 4; ++q) {
      int m = mBlk + r0 + q * 8;
      int b = m >> 10, y = (m >> 5) & 31, x = m & 31;
      arow[q] = ((b * WPAD + y + BRD) * WPAD + (x + BRD)) * 256 + chunk * 8;
    }
  }
  int brow[BQ];
  {
    const int r0 = nBlk + wave * BRW + (lane >> 3);
#pragma unroll
    for (int q = 0; q < BQ; ++q)
      brow[q] = (r0 + q * 8) * K + (lane & 7) * 8;
  }

  floatx4 acc[4][NI] = {};
  u16* adst = &Alds[wave * 32 * 64];
  u16* bdst = &Blds[wave * BRW * 64];

  for (int kt = 0; kt < 36; ++kt) {
    const int tap = kt >> 2, c0 = (kt & 3) << 6;
    const int kh = tap / 3, kw = tap - kh * 3;
    const int koff = (kh * WPAD + kw) * 256 + c0;
#pragma unroll
    for (int q = 0; q < 4; ++q)
      gload16(img + (arow[q] + koff), adst + q * 512);
#pragma unroll
    for (int q = 0; q < BQ; ++q)
      gload16(wB + (brow[q] + kt * 64), bdst + q * 512);
    __syncthreads();
#pragma unroll
    for (int kk = 0; kk < 2; ++kk) {
      const int sx = ((kk * 4 + (lane >> 4)) ^ (lane & 7)) << 3;
      half8 af[4], bfr[NI];
#pragma unroll
      for (int mi = 0; mi < 4; ++mi)
        af[mi] = *(const half8*)&Alds[(wm * 64 + mi * 16 + (lane & 15)) * 64 + sx];
#pragma unroll
      for (int ni = 0; ni < NI; ++ni)
        bfr[ni] = *(const half8*)&Blds[(wn * (BN / 2) + ni * 16 + (lane & 15)) * 64 + sx];
#pragma unroll
      for (int mi = 0; mi < 4; ++mi)
#pragma unroll
        for (int ni = 0; ni < NI; ++ni)
          acc[mi][ni] = __builtin_amdgcn_mfma_f32_16x16x32_f16(af[mi], bfr[ni], acc[mi][ni], 0, 0, 0);
    }
    __syncthreads();
  }

#pragma unroll
  for (int ni = 0; ni < NI; ++ni) {
    const int n = nBlk + wn * (BN / 2) + ni * 16 + (lane & 15);
    float sc = 0.f, bi = 0.f;
    if constexpr (EPI == 0 || EPI == 2) { sc = p0[n]; bi = p1[n]; }
    else { sc = (n < 50) ? p0[n] : 0.f; }
#pragma unroll
    for (int mi = 0; mi < 4; ++mi) {
      const int mb = mBlk + wm * 64 + mi * 16 + ((lane >> 4) << 2);
      if constexpr (EPI == 0) {
        u16* ym = (u16*)dst;
#pragma unroll
        for (int r = 0; r < 4; ++r) {
          int m = mb + r;
          int b = m >> 10, yy = (m >> 5) & 31, xx = m & 31;
          float v = fmaxf(acc[mi][ni][r] * sc + bi, 0.f);
          ym[((b * 34 + yy + 1) * 34 + (xx + 1)) * 256 + n] = f2h(v);
        }
      } else if constexpr (EPI == 1) {
        float* ob = (float*)dst;
#pragma unroll
        for (int r = 0; r < 4; ++r)
          ob[(mb + r) * 64 + n] = acc[mi][ni][r] + sc;
      } else {
        int b = mb >> 10, s = mb & 1023;
        const float* xr = xorig + ((b * 256 + n) << 10) + s;
        float* orow = (float*)dst + ((b * 256 + n) << 10) + s;
        floatx4 xv = *(const floatx4*)xr;
        floatx4 res;
#pragma unroll
        for (int r = 0; r < 4; ++r)
          res[r] = fmaxf(acc[mi][ni][r] * sc + bi + xv[r], 0.f);
        *(floatx4*)orow = res;
      }
    }
  }
}

// ---------------- deformable conv ----------------
struct Geo { float w00, w01, w10, w11; int base; };

__device__ __forceinline__ Geo mkgeo(int soh, int sow, int ti, int tj, float2 ov) {
  float py = (float)(soh - 2 + ti) + ov.x;
  float px = (float)(sow - 2 + tj) + ov.y;
  // zero-outside bilinear == clamp into [-1,32] vs border-2 zero-padded image
  py = fminf(32.f, fmaxf(-1.f, py));
  px = fminf(32.f, fmaxf(-1.f, px));
  float fy = floorf(py), fx = floorf(px);
  float wy1 = py - fy, wx1 = px - fx;
  float wy0 = 1.f - wy1, wx0 = 1.f - wx1;
  Geo g;
  g.w00 = wy0 * wx0; g.w01 = wy0 * wx1; g.w10 = wy1 * wx0; g.w11 = wy1 * wx1;
  g.base = (((int)fy + 2) * 36 + ((int)fx + 2)) * 256;
  return g;
}

struct Corners { half8 v00[2], v01[2], v10[2], v11[2]; };

__device__ __forceinline__ Corners loadC(const u16* __restrict__ pb) {
  Corners c;
#pragma unroll
  for (int gg = 0; gg < 2; ++gg) {
    c.v00[gg] = *(const half8*)(pb + gg * 8);
    c.v01[gg] = *(const half8*)(pb + gg * 8 + 256);
    c.v10[gg] = *(const half8*)(pb + gg * 8 + 9216);
    c.v11[gg] = *(const half8*)(pb + gg * 8 + 9472);
  }
  return c;
}

__device__ __forceinline__ void blendStore(const Corners& c, const Geo& g,
                                           int scg, int srow, u16* __restrict__ adst) {
  _Float16 h00 = (_Float16)g.w00, h01 = (_Float16)g.w01;
  _Float16 h10 = (_Float16)g.w10, h11 = (_Float16)g.w11;
#pragma unroll
  for (int gg = 0; gg < 2; ++gg) {
    half8 r = c.v00[gg] * h00 + c.v01[gg] * h01 + c.v10[gg] * h10 + c.v11[gg] * h11;
    int slot = (scg * 2 + gg) ^ (srow & 7);
    *(half8*)&adst[srow * 64 + slot * 8] = r;
  }
}

// M-tile 64, N=256. ONE barrier per kt: A and per-wave B regions double-
// buffered (LDS 81920 B = exactly 2 blocks/CU). Per iter: issue corners[kt+1]
// (8 loads, oldest), issue B[kt+1] DMA, MFMA[kt] (operands one barrier old),
// blend[kt+1] (s_waitcnt vmcnt(8) -> corner latency hidden behind MFMA),
// store A[kt+1], barrier (vmcnt0 drain covers B DMA issued a phase earlier).
__global__ __launch_bounds__(256) void deform_kernel(
    const u16* __restrict__ xp, const u16* __restrict__ wB,
    const float* __restrict__ offb,
    const float* __restrict__ sc3, const float* __restrict__ bi3,
    u16* __restrict__ ymid)
{
  constexpr int K = 6400;
  const int t = threadIdx.x;
  const int wave = t >> 6, lane = t & 63;
  const int phys = blockIdx.x;
  const int mBlk = ((phys & 7) * 64 + (phys >> 3)) * 64;   // XCD-contiguous

  __shared__ u16 Alds[2][64 * 64];     // 16 KB
  __shared__ u16 Blds[2][256 * 64];    // 64 KB

  const int srow = t >> 2, scg = t & 3;       // 4 lanes share a row: coalesced corners
  const int sm = mBlk + srow;
  const int sb = sm >> 10, soh = (sm >> 5) & 31, sow = sm & 31;
  const u16* ximg = xp + sb * (36 * 36 * 256) + scg * 16;
  const float2* offrow = (const float2*)(offb + sm * 64);

  const int brow = (wave * 64 + (lane >> 3)) * K + (lane & 7) * 8;

  floatx4 acc[4][4] = {};

  // prologue: sample + stage kt=0 into buffer 0
  Geo g = mkgeo(soh, sow, 0, 0, offrow[0]);
  {
    Corners c = loadC(ximg + g.base);
#pragma unroll
    for (int q = 0; q < 8; ++q)
      gload16(wB + (brow + q * 8 * K), &Blds[0][wave * 4096] + q * 512);
    blendStore(c, g, scg, srow, &Alds[0][0]);
  }
  __syncthreads();

  for (int tap = 0; tap < 25; ++tap) {
#pragma unroll
    for (int cc = 0; cc < 4; ++cc) {
      const int kt = tap * 4 + cc;
      const int buf = kt & 1, nbuf = buf ^ 1;
      // next-sample geometry (tap 24/cc 3 -> offrow[25] = zeros, clamped: safe)
      Geo gn; int sccn;
      if (cc < 3) { gn = g; sccn = cc + 1; }
      else {
        const int tn = tap + 1;
        const int tin = tn / 5, tjn = tn - tin * 5;
        gn = mkgeo(soh, sow, tin, tjn, offrow[tn]);
        sccn = 0;
      }
      // corner loads first (oldest in vmcnt queue)
      Corners cn = loadC(ximg + gn.base + sccn * 64);
      // B[kt+1] DMA into the other per-wave region (kt=99 -> wB2 region, unused)
#pragma unroll
      for (int q = 0; q < 8; ++q)
        gload16(wB + (brow + q * 8 * K + (kt + 1) * 64),
                &Blds[nbuf][wave * 4096] + q * 512);
      // MFMA[kt] — operands written before the previous barrier
      const u16* ab = &Alds[buf][0];
      const u16* bb = &Blds[buf][0];
#pragma unroll
      for (int kk = 0; kk < 2; ++kk) {
        const int sx = ((kk * 4 + (lane >> 4)) ^ (lane & 7)) << 3;
        half8 af[4], bfr[4];
#pragma unroll
        for (int mi = 0; mi < 4; ++mi)
          af[mi] = *(const half8*)&ab[(mi * 16 + (lane & 15)) * 64 + sx];
#pragma unroll
        for (int ni = 0; ni < 4; ++ni)
          bfr[ni] = *(const half8*)&bb[(wave * 64 + ni * 16 + (lane & 15)) * 64 + sx];
#pragma unroll
        for (int mi = 0; mi < 4; ++mi)
#pragma unroll
          for (int ni = 0; ni < 4; ++ni)
            acc[mi][ni] = __builtin_amdgcn_mfma_f32_16x16x32_f16(af[mi], bfr[ni], acc[mi][ni], 0, 0, 0);
      }
      // blend kt+1 (vmcnt(8): waits corners only) + store into A[nbuf]
      blendStore(cn, gn, scg, srow, &Alds[nbuf][0]);
      g = gn;
      __syncthreads();
    }
  }

#pragma unroll
  for (int ni = 0; ni < 4; ++ni) {
    const int n = wave * 64 + ni * 16 + (lane & 15);
    float sc = sc3[n], bi = bi3[n];
#pragma unroll
    for (int mi = 0; mi < 4; ++mi) {
      const int mb = mBlk + mi * 16 + ((lane >> 4) << 2);
#pragma unroll
      for (int r = 0; r < 4; ++r) {
        int m = mb + r;
        int b = m >> 10, yy = (m >> 5) & 31, xx = m & 31;
        int idx = ((b * 34 + yy + 1) * 34 + (xx + 1)) * 256 + n;
        float v = fmaxf(acc[mi][ni][r] * sc + bi, 0.f) + h2f(ymid[idx]);
        ymid[idx] = f2h(v);
      }
    }
  }
}

// ---------------- launch ----------------
extern "C" void kernel_launch(void* const* d_in, const int* in_sizes, int n_in,
                              void* d_out, int out_size, void* d_ws, size_t ws_size,
                              hipStream_t stream)
{
  const float* x    = (const float*)d_in[0];
  const float* w1   = (const float*)d_in[1];
  const float* woff = (const float*)d_in[2];
  const float* boff = (const float*)d_in[3];
  const float* w3   = (const float*)d_in[4];
  const float* w2   = (const float*)d_in[5];
  const float* g1 = (const float*)d_in[6],  *b1 = (const float*)d_in[7];
  const float* m1 = (const float*)d_in[8],  *v1 = (const float*)d_in[9];
  const float* g3 = (const float*)d_in[10], *b3 = (const float*)d_in[11];
  const float* m3 = (const float*)d_in[12], *v3 = (const float*)d_in[13];
  const float* g2 = (const float*)d_in[14], *b2 = (const float*)d_in[15];
  const float* m2 = (const float*)d_in[16], *v2 = (const float*)d_in[17];

  char* ws = (char*)d_ws;
  u16*   xp   = (u16*)(ws + OFF_XP);
  u16*   ymid = (u16*)(ws + OFF_YMID);
  float* offb = (float*)(ws + OFF_OFFB);
  u16*   wB1  = (u16*)(ws + OFF_WB1);
  u16*   wBo  = (u16*)(ws + OFF_WBO);
  u16*   wB3  = (u16*)(ws + OFF_WB3);
  u16*   wB2  = (u16*)(ws + OFF_WB2);
  float* bnp  = (float*)(ws + OFF_BNP);

  zero_kernel<<<9808, 256, 0, stream>>>((uintx4*)ws, 2510848);
  prep_kernel<<<11590, 256, 0, stream>>>(w1, woff, w3, w2,
                                         g1, b1, m1, v1, g3, b3, m3, v3,
                                         g2, b2, m2, v2,
                                         wB1, wBo, wB3, wB2, bnp);
  pack_x_kernel<<<1024, 256, 0, stream>>>(x, xp);
  conv3x3_kernel<64, 1, 36, 1><<<dim3(1, 256), 256, 0, stream>>>(
      xp, wBo, boff, nullptr, nullptr, (void*)offb);
  conv3x3_kernel<128, 2, 36, 0><<<dim3(2, 256), 256, 0, stream>>>(
      xp, wB1, bnp + 0, bnp + 256, nullptr, (void*)ymid);
  deform_kernel<<<512, 256, 0, stream>>>(xp, wB3, offb, bnp + 512, bnp + 768, ymid);
  conv3x3_kernel<128, 2, 34, 2><<<dim3(2, 256), 256, 0, stream>>>(
      ymid, wB2, bnp + 1024, bnp + 1280, x, d_out);
}

// Round 7
// 444.948 us; speedup vs baseline: 1.0019x; 1.0019x over previous
//
#include <hip/hip_runtime.h>

typedef unsigned short u16;
typedef unsigned int u32;
typedef __attribute__((ext_vector_type(8))) _Float16 half8;
typedef __attribute__((ext_vector_type(4))) float floatx4;
typedef __attribute__((ext_vector_type(4))) u32 uintx4;

// ---------------- helpers ----------------
__device__ __forceinline__ u16 f2h(float f) {
  union { _Float16 h; u16 u; } v; v.h = (_Float16)f; return v.u;
}
__device__ __forceinline__ float h2f(u16 u) {
  union { u16 u; _Float16 h; } v; v.u = u; return (float)v.h;
}

typedef __attribute__((address_space(1))) const void* as1cv;
typedef __attribute__((address_space(3))) void* as3v;
__device__ __forceinline__ void gload16(const void* g, void* l) {
  __builtin_amdgcn_global_load_lds((as1cv)g, (as3v)l, 16, 0, 0);
}

// ---------------- ws layout (bytes) ----------------
static constexpr size_t OFF_XP   = 0;         // [32][36][36][256] f16
static constexpr size_t OFF_YMID = 21233664;  // [32][34][34][256] f16
static constexpr size_t OFF_OFFB = 40173568;  // [32768][64] f32
static constexpr size_t OFF_WB1  = 48562176;  // [256][2304] f16 (swizzled)
static constexpr size_t OFF_WBO  = 49741824;  // [64][2304] f16 (swizzled)
static constexpr size_t OFF_WB3  = 50036736;  // [256][6400] f16 (swizzled)
static constexpr size_t OFF_WB2  = 53313536;  // [256][2304] f16 (swizzled)
static constexpr size_t OFF_BNP  = 54493184;  // [6][256] f32

// ---------------- zero fill ----------------
__global__ __launch_bounds__(256) void zero_kernel(uintx4* __restrict__ p, int n) {
  int i = blockIdx.x * 256 + threadIdx.x;
  if (i < n) { uintx4 z = {0u, 0u, 0u, 0u}; p[i] = z; }
}

// ---------------- pack weights (XOR-swizzled) + bn params ----------------
// packed[p][kt*64 + slot*8 + j] = orig channel-group (slot ^ (p&7)) of
// 64-ch window (kt&3), tap (kt>>2). Readers XOR slot with (row&7).
__global__ __launch_bounds__(256) void prep_kernel(
    const float* __restrict__ w1, const float* __restrict__ woff,
    const float* __restrict__ w3, const float* __restrict__ w2,
    const float* __restrict__ g1, const float* __restrict__ b1,
    const float* __restrict__ m1, const float* __restrict__ v1,
    const float* __restrict__ g3, const float* __restrict__ b3,
    const float* __restrict__ m3, const float* __restrict__ v3,
    const float* __restrict__ g2, const float* __restrict__ b2,
    const float* __restrict__ m2, const float* __restrict__ v2,
    u16* __restrict__ wB1, u16* __restrict__ wBo,
    u16* __restrict__ wB3, u16* __restrict__ wB2,
    float* __restrict__ bnp)
{
  int i = blockIdx.x * 256 + threadIdx.x;
  if (i < 589824) {                    // wB1 [256][2304]
    int p = i / 2304, kcol = i - p * 2304;
    int kt = kcol >> 6, slot = (kcol >> 3) & 7, j = kcol & 7;
    int c = ((kt & 3) << 6) + ((slot ^ (p & 7)) << 3) + j;
    wB1[i] = f2h(w1[(p * 256 + c) * 9 + (kt >> 2)]);
    return;
  }
  i -= 589824;
  if (i < 147456) {                    // wBo [64][2304] (rows >= 50 zero)
    int p = i / 2304, kcol = i - p * 2304;
    int kt = kcol >> 6, slot = (kcol >> 3) & 7, j = kcol & 7;
    int c = ((kt & 3) << 6) + ((slot ^ (p & 7)) << 3) + j;
    wBo[i] = (p < 50) ? f2h(woff[(p * 256 + c) * 9 + (kt >> 2)]) : (u16)0;
    return;
  }
  i -= 147456;
  if (i < 1638400) {                   // wB3 [256][6400]
    int p = i / 6400, kcol = i - p * 6400;
    int kt = kcol >> 6, slot = (kcol >> 3) & 7, j = kcol & 7;
    int c = ((kt & 3) << 6) + ((slot ^ (p & 7)) << 3) + j;
    wB3[i] = f2h(w3[(p * 256 + c) * 25 + (kt >> 2)]);
    return;
  }
  i -= 1638400;
  if (i < 589824) {                    // wB2
    int p = i / 2304, kcol = i - p * 2304;
    int kt = kcol >> 6, slot = (kcol >> 3) & 7, j = kcol & 7;
    int c = ((kt & 3) << 6) + ((slot ^ (p & 7)) << 3) + j;
    wB2[i] = f2h(w2[(p * 256 + c) * 9 + (kt >> 2)]);
    return;
  }
  i -= 589824;
  if (i < 1536) {                      // bn params
    int grp = i >> 8, n = i & 255;
    const float* g  = (grp < 2) ? g1 : (grp < 4) ? g3 : g2;
    const float* bb = (grp < 2) ? b1 : (grp < 4) ? b3 : b2;
    const float* mm = (grp < 2) ? m1 : (grp < 4) ? m3 : m2;
    const float* vv = (grp < 2) ? v1 : (grp < 4) ? v3 : v2;
    float sc = g[n] / sqrtf(vv[n] + 1e-5f);
    bnp[i] = (grp & 1) ? (bb[n] - mm[n] * sc) : sc;
  }
}

// ---------------- pack x: NCHW f32 -> NHWC f16 border-2 ----------------
__global__ __launch_bounds__(256) void pack_x_kernel(const float* __restrict__ x,
                                                     u16* __restrict__ xp)
{
  __shared__ float trans[256][33];
  int b = blockIdx.x >> 5, y = blockIdx.x & 31;
  int t = threadIdx.x;
  int xi = t & 31, ch = t >> 5;
  const float* src = x + (b * 256 * 1024) + y * 32 + xi;
#pragma unroll 4
  for (int c8 = 0; c8 < 32; ++c8) {
    int c = c8 * 8 + ch;
    trans[c][xi] = src[c * 1024];
  }
  __syncthreads();
  u16* dstrow = xp + ((b * 36 + y + 2) * 36 + 2) * 256 + t;
#pragma unroll 4
  for (int xx = 0; xx < 32; ++xx)
    dstrow[xx * 256] = f2h(trans[t][xx]);
}

// ---------------- implicit-GEMM 3x3 conv ----------------
// XCD-aware swizzle: (phys&7)*per + (phys>>3) -> contiguous m-range per XCD.
template <int BN, int NBX, int WPAD, int EPI>
__global__ __launch_bounds__(256) void conv3x3_kernel(
    const u16* __restrict__ img, const u16* __restrict__ wB,
    const float* __restrict__ p0, const float* __restrict__ p1,
    const float* __restrict__ xorig, void* __restrict__ dst)
{
  constexpr int K = 2304;
  constexpr int NI = BN / 32;
  constexpr int BQ = BN / 32;
  constexpr int BRW = BN / 4;
  constexpr int BRD = (WPAD - 34) / 2;
  constexpr int PER = (NBX * 256) / 8;

  const int t = threadIdx.x;
  const int wave = t >> 6, lane = t & 63;
  const int lin = blockIdx.y * NBX + blockIdx.x;
  const int swz = (lin & 7) * PER + (lin >> 3);
  const int mBlk = (swz / NBX) * 128;
  const int nBlk = (swz % NBX) * BN;
  const int wm = wave >> 1, wn = wave & 1;

  __shared__ u16 Alds[128 * 64];
  __shared__ u16 Blds[BN * 64];

  int arow[4];
  {
    const int r0 = wave * 32 + (lane >> 3);
    const int chunk = (lane & 7) ^ (lane >> 3);   // XOR-swizzled source chunk
#pragma unroll
    for (int q = 0; q < 4; ++q) {
      int m = mBlk + r0 + q * 8;
      int b = m >> 10, y = (m >> 5) & 31, x = m & 31;
      arow[q] = ((b * WPAD + y + BRD) * WPAD + (x + BRD)) * 256 + chunk * 8;
    }
  }
  int brow[BQ];
  {
    const int r0 = nBlk + wave * BRW + (lane >> 3);
#pragma unroll
    for (int q = 0; q < BQ; ++q)
      brow[q] = (r0 + q * 8) * K + (lane & 7) * 8;
  }

  floatx4 acc[4][NI] = {};
  u16* adst = &Alds[wave * 32 * 64];
  u16* bdst = &Blds[wave * BRW * 64];

  for (int kt = 0; kt < 36; ++kt) {
    const int tap = kt >> 2, c0 = (kt & 3) << 6;
    const int kh = tap / 3, kw = tap - kh * 3;
    const int koff = (kh * WPAD + kw) * 256 + c0;
#pragma unroll
    for (int q = 0; q < 4; ++q)
      gload16(img + (arow[q] + koff), adst + q * 512);
#pragma unroll
    for (int q = 0; q < BQ; ++q)
      gload16(wB + (brow[q] + kt * 64), bdst + q * 512);
    __syncthreads();
#pragma unroll
    for (int kk = 0; kk < 2; ++kk) {
      const int sx = ((kk * 4 + (lane >> 4)) ^ (lane & 7)) << 3;
      half8 af[4], bfr[NI];
#pragma unroll
      for (int mi = 0; mi < 4; ++mi)
        af[mi] = *(const half8*)&Alds[(wm * 64 + mi * 16 + (lane & 15)) * 64 + sx];
#pragma unroll
      for (int ni = 0; ni < NI; ++ni)
        bfr[ni] = *(const half8*)&Blds[(wn * (BN / 2) + ni * 16 + (lane & 15)) * 64 + sx];
#pragma unroll
      for (int mi = 0; mi < 4; ++mi)
#pragma unroll
        for (int ni = 0; ni < NI; ++ni)
          acc[mi][ni] = __builtin_amdgcn_mfma_f32_16x16x32_f16(af[mi], bfr[ni], acc[mi][ni], 0, 0, 0);
    }
    __syncthreads();
  }

#pragma unroll
  for (int ni = 0; ni < NI; ++ni) {
    const int n = nBlk + wn * (BN / 2) + ni * 16 + (lane & 15);
    float sc = 0.f, bi = 0.f;
    if constexpr (EPI == 0 || EPI == 2) { sc = p0[n]; bi = p1[n]; }
    else { sc = (n < 50) ? p0[n] : 0.f; }
#pragma unroll
    for (int mi = 0; mi < 4; ++mi) {
      const int mb = mBlk + wm * 64 + mi * 16 + ((lane >> 4) << 2);
      if constexpr (EPI == 0) {
        u16* ym = (u16*)dst;
#pragma unroll
        for (int r = 0; r < 4; ++r) {
          int m = mb + r;
          int b = m >> 10, yy = (m >> 5) & 31, xx = m & 31;
          float v = fmaxf(acc[mi][ni][r] * sc + bi, 0.f);
          ym[((b * 34 + yy + 1) * 34 + (xx + 1)) * 256 + n] = f2h(v);
        }
      } else if constexpr (EPI == 1) {
        float* ob = (float*)dst;
#pragma unroll
        for (int r = 0; r < 4; ++r)
          ob[(mb + r) * 64 + n] = acc[mi][ni][r] + sc;
      } else {
        int b = mb >> 10, s = mb & 1023;
        const float* xr = xorig + ((b * 256 + n) << 10) + s;
        float* orow = (float*)dst + ((b * 256 + n) << 10) + s;
        floatx4 xv = *(const floatx4*)xr;
        floatx4 res;
#pragma unroll
        for (int r = 0; r < 4; ++r)
          res[r] = fmaxf(acc[mi][ni][r] * sc + bi + xv[r], 0.f);
        *(floatx4*)orow = res;
      }
    }
  }
}

// ---------------- deformable conv ----------------
struct Geo { float w00, w01, w10, w11; int base; };

__device__ __forceinline__ Geo mkgeo(int soh, int sow, int ti, int tj, float2 ov) {
  float py = (float)(soh - 2 + ti) + ov.x;
  float px = (float)(sow - 2 + tj) + ov.y;
  // zero-outside bilinear == clamp into [-1,32] vs border-2 zero-padded image
  py = fminf(32.f, fmaxf(-1.f, py));
  px = fminf(32.f, fmaxf(-1.f, px));
  float fy = floorf(py), fx = floorf(px);
  float wy1 = py - fy, wx1 = px - fx;
  float wy0 = 1.f - wy1, wx0 = 1.f - wx1;
  Geo g;
  g.w00 = wy0 * wx0; g.w01 = wy0 * wx1; g.w10 = wy1 * wx0; g.w11 = wy1 * wx1;
  g.base = (((int)fy + 2) * 36 + ((int)fx + 2)) * 256;
  return g;
}

struct Corners { half8 v00[2], v01[2], v10[2], v11[2]; };

__device__ __forceinline__ Corners loadC(const u16* __restrict__ pb) {
  Corners c;
#pragma unroll
  for (int gg = 0; gg < 2; ++gg) {
    c.v00[gg] = *(const half8*)(pb + gg * 8);
    c.v01[gg] = *(const half8*)(pb + gg * 8 + 256);
    c.v10[gg] = *(const half8*)(pb + gg * 8 + 9216);
    c.v11[gg] = *(const half8*)(pb + gg * 8 + 9472);
  }
  return c;
}

__device__ __forceinline__ void blendStore(const Corners& c, const Geo& g,
                                           int scg, int srow, u16* __restrict__ adst) {
  _Float16 h00 = (_Float16)g.w00, h01 = (_Float16)g.w01;
  _Float16 h10 = (_Float16)g.w10, h11 = (_Float16)g.w11;
#pragma unroll
  for (int gg = 0; gg < 2; ++gg) {
    half8 r = c.v00[gg] * h00 + c.v01[gg] * h01 + c.v10[gg] * h10 + c.v11[gg] * h11;
    int slot = (scg * 2 + gg) ^ (srow & 7);
    *(half8*)&adst[srow * 64 + slot * 8] = r;
  }
}

// M-tile 128, N=256, 512 threads (8 waves = 2m x 4n, acc[4][4] each).
// R5-proven loop: corners -> B DMA -> blend/store -> barrier -> MFMA -> barrier.
// Rationale: deform is L2-BW-bound (3.28 GB L2 traffic at M=64); M=128 halves
// the B-weight stream (each block reads wB3 once for 2x the output) -> 2.46 GB.
// Wave count/CU unchanged: 256 blocks x 8 waves = 8 waves/CU.
__global__ __launch_bounds__(512) void deform_kernel(
    const u16* __restrict__ xp, const u16* __restrict__ wB,
    const float* __restrict__ offb,
    const float* __restrict__ sc3, const float* __restrict__ bi3,
    u16* __restrict__ ymid)
{
  constexpr int K = 6400;
  const int t = threadIdx.x;
  const int wave = t >> 6, lane = t & 63;
  const int phys = blockIdx.x;
  const int mBlk = ((phys & 7) * 32 + (phys >> 3)) * 128;  // XCD-contiguous
  const int wm = wave >> 2, wn = wave & 3;

  __shared__ u16 Alds[128 * 64];   // 16 KB
  __shared__ u16 Blds[256 * 64];   // 32 KB

  const int srow = t >> 2, scg = t & 3;       // 4 lanes share a row: coalesced corners
  const int sm = mBlk + srow;
  const int sb = sm >> 10, soh = (sm >> 5) & 31, sow = sm & 31;
  const u16* ximg = xp + sb * (36 * 36 * 256) + scg * 16;
  const float2* offrow = (const float2*)(offb + sm * 64);

  // B staging: 32 rows per wave, 4 gload16 per thread
  const int brow = (wave * 32 + (lane >> 3)) * K + (lane & 7) * 8;
  u16* bdst = &Blds[wave * 32 * 64];

  floatx4 acc[4][4] = {};

  for (int tap = 0; tap < 25; ++tap) {
    const int ti = tap / 5, tj = tap - ti * 5;
    const Geo g = mkgeo(soh, sow, ti, tj, offrow[tap]);
#pragma unroll
    for (int cc = 0; cc < 4; ++cc) {
      const int kt = tap * 4 + cc;
      // corner loads first (blend waits only these in the vmcnt queue)
      Corners c = loadC(ximg + g.base + cc * 64);
      // B staging (drained by the barrier, overlaps the blend)
#pragma unroll
      for (int q = 0; q < 4; ++q)
        gload16(wB + (brow + q * 8 * K + kt * 64), bdst + q * 512);
      blendStore(c, g, scg, srow, Alds);
      __syncthreads();
#pragma unroll
      for (int kk = 0; kk < 2; ++kk) {
        const int sx = ((kk * 4 + (lane >> 4)) ^ (lane & 7)) << 3;
        half8 af[4], bfr[4];
#pragma unroll
        for (int mi = 0; mi < 4; ++mi)
          af[mi] = *(const half8*)&Alds[(wm * 64 + mi * 16 + (lane & 15)) * 64 + sx];
#pragma unroll
        for (int ni = 0; ni < 4; ++ni)
          bfr[ni] = *(const half8*)&Blds[(wn * 64 + ni * 16 + (lane & 15)) * 64 + sx];
#pragma unroll
        for (int mi = 0; mi < 4; ++mi)
#pragma unroll
          for (int ni = 0; ni < 4; ++ni)
            acc[mi][ni] = __builtin_amdgcn_mfma_f32_16x16x32_f16(af[mi], bfr[ni], acc[mi][ni], 0, 0, 0);
      }
      __syncthreads();
    }
  }

#pragma unroll
  for (int ni = 0; ni < 4; ++ni) {
    const int n = wn * 64 + ni * 16 + (lane & 15);
    float sc = sc3[n], bi = bi3[n];
#pragma unroll
    for (int mi = 0; mi < 4; ++mi) {
      const int mb = mBlk + wm * 64 + mi * 16 + ((lane >> 4) << 2);
#pragma unroll
      for (int r = 0; r < 4; ++r) {
        int m = mb + r;
        int b = m >> 10, yy = (m >> 5) & 31, xx = m & 31;
        int idx = ((b * 34 + yy + 1) * 34 + (xx + 1)) * 256 + n;
        float v = fmaxf(acc[mi][ni][r] * sc + bi, 0.f) + h2f(ymid[idx]);
        ymid[idx] = f2h(v);
      }
    }
  }
}

// ---------------- launch ----------------
extern "C" void kernel_launch(void* const* d_in, const int* in_sizes, int n_in,
                              void* d_out, int out_size, void* d_ws, size_t ws_size,
                              hipStream_t stream)
{
  const float* x    = (const float*)d_in[0];
  const float* w1   = (const float*)d_in[1];
  const float* woff = (const float*)d_in[2];
  const float* boff = (const float*)d_in[3];
  const float* w3   = (const float*)d_in[4];
  const float* w2   = (const float*)d_in[5];
  const float* g1 = (const float*)d_in[6],  *b1 = (const float*)d_in[7];
  const float* m1 = (const float*)d_in[8],  *v1 = (const float*)d_in[9];
  const float* g3 = (const float*)d_in[10], *b3 = (const float*)d_in[11];
  const float* m3 = (const float*)d_in[12], *v3 = (const float*)d_in[13];
  const float* g2 = (const float*)d_in[14], *b2 = (const float*)d_in[15];
  const float* m2 = (const float*)d_in[16], *v2 = (const float*)d_in[17];

  char* ws = (char*)d_ws;
  u16*   xp   = (u16*)(ws + OFF_XP);
  u16*   ymid = (u16*)(ws + OFF_YMID);
  float* offb = (float*)(ws + OFF_OFFB);
  u16*   wB1  = (u16*)(ws + OFF_WB1);
  u16*   wBo  = (u16*)(ws + OFF_WBO);
  u16*   wB3  = (u16*)(ws + OFF_WB3);
  u16*   wB2  = (u16*)(ws + OFF_WB2);
  float* bnp  = (float*)(ws + OFF_BNP);

  zero_kernel<<<9808, 256, 0, stream>>>((uintx4*)ws, 2510848);
  prep_kernel<<<11590, 256, 0, stream>>>(w1, woff, w3, w2,
                                         g1, b1, m1, v1, g3, b3, m3, v3,
                                         g2, b2, m2, v2,
                                         wB1, wBo, wB3, wB2, bnp);
  pack_x_kernel<<<1024, 256, 0, stream>>>(x, xp);
  conv3x3_kernel<64, 1, 36, 1><<<dim3(1, 256), 256, 0, stream>>>(
      xp, wBo, boff, nullptr, nullptr, (void*)offb);
  conv3x3_kernel<128, 2, 36, 0><<<dim3(2, 256), 256, 0, stream>>>(
      xp, wB1, bnp + 0, bnp + 256, nullptr, (void*)ymid);
  deform_kernel<<<256, 512, 0, stream>>>(xp, wB3, offb, bnp + 512, bnp + 768, ymid);
  conv3x3_kernel<128, 2, 34, 2><<<dim3(2, 256), 256, 0, stream>>>(
      ymid, wB2, bnp + 1024, bnp + 1280, x, d_out);
}

// Round 8
// 425.230 us; speedup vs baseline: 1.0484x; 1.0464x over previous
//
#include <hip/hip_runtime.h>

typedef unsigned short u16;
typedef unsigned int u32;
typedef __attribute__((ext_vector_type(8))) _Float16 half8;
typedef __attribute__((ext_vector_type(4))) float floatx4;
typedef __attribute__((ext_vector_type(4))) u32 uintx4;

// ---------------- helpers ----------------
__device__ __forceinline__ u16 f2h(float f) {
  union { _Float16 h; u16 u; } v; v.h = (_Float16)f; return v.u;
}
__device__ __forceinline__ float h2f(u16 u) {
  union { u16 u; _Float16 h; } v; v.u = u; return (float)v.h;
}

typedef __attribute__((address_space(1))) const void* as1cv;
typedef __attribute__((address_space(3))) void* as3v;
__device__ __forceinline__ void gload16(const void* g, void* l) {
  __builtin_amdgcn_global_load_lds((as1cv)g, (as3v)l, 16, 0, 0);
}

// ---------------- ws layout (bytes) ----------------
static constexpr size_t OFF_XP   = 0;         // [32][36][36][256] f16
static constexpr size_t OFF_YMID = 21233664;  // [32][34][34][256] f16
static constexpr size_t OFF_OFFB = 40173568;  // [32768][64] f32
static constexpr size_t OFF_WB1  = 48562176;  // [256][2304] f16 (swizzled)
static constexpr size_t OFF_WBO  = 49741824;  // [64][2304] f16 (swizzled)
static constexpr size_t OFF_WB3  = 50036736;  // [256][6400] f16 (swizzled)
static constexpr size_t OFF_WB2  = 53313536;  // [256][2304] f16 (swizzled)
static constexpr size_t OFF_BNP  = 54493184;  // [6][256] f32

// ---------------- zero fill ----------------
__global__ __launch_bounds__(256) void zero_kernel(uintx4* __restrict__ p, int n) {
  int i = blockIdx.x * 256 + threadIdx.x;
  if (i < n) { uintx4 z = {0u, 0u, 0u, 0u}; p[i] = z; }
}

// ---------------- pack weights (XOR-swizzled) + bn params ----------------
// packed[p][kt*64 + slot*8 + j] = orig channel-group (slot ^ (p&7)) of
// 64-ch window (kt&3), tap (kt>>2). Readers XOR slot with (row&7).
__global__ __launch_bounds__(256) void prep_kernel(
    const float* __restrict__ w1, const float* __restrict__ woff,
    const float* __restrict__ w3, const float* __restrict__ w2,
    const float* __restrict__ g1, const float* __restrict__ b1,
    const float* __restrict__ m1, const float* __restrict__ v1,
    const float* __restrict__ g3, const float* __restrict__ b3,
    const float* __restrict__ m3, const float* __restrict__ v3,
    const float* __restrict__ g2, const float* __restrict__ b2,
    const float* __restrict__ m2, const float* __restrict__ v2,
    u16* __restrict__ wB1, u16* __restrict__ wBo,
    u16* __restrict__ wB3, u16* __restrict__ wB2,
    float* __restrict__ bnp)
{
  int i = blockIdx.x * 256 + threadIdx.x;
  if (i < 589824) {                    // wB1 [256][2304]
    int p = i / 2304, kcol = i - p * 2304;
    int kt = kcol >> 6, slot = (kcol >> 3) & 7, j = kcol & 7;
    int c = ((kt & 3) << 6) + ((slot ^ (p & 7)) << 3) + j;
    wB1[i] = f2h(w1[(p * 256 + c) * 9 + (kt >> 2)]);
    return;
  }
  i -= 589824;
  if (i < 147456) {                    // wBo [64][2304] (rows >= 50 zero)
    int p = i / 2304, kcol = i - p * 2304;
    int kt = kcol >> 6, slot = (kcol >> 3) & 7, j = kcol & 7;
    int c = ((kt & 3) << 6) + ((slot ^ (p & 7)) << 3) + j;
    wBo[i] = (p < 50) ? f2h(woff[(p * 256 + c) * 9 + (kt >> 2)]) : (u16)0;
    return;
  }
  i -= 147456;
  if (i < 1638400) {                   // wB3 [256][6400]
    int p = i / 6400, kcol = i - p * 6400;
    int kt = kcol >> 6, slot = (kcol >> 3) & 7, j = kcol & 7;
    int c = ((kt & 3) << 6) + ((slot ^ (p & 7)) << 3) + j;
    wB3[i] = f2h(w3[(p * 256 + c) * 25 + (kt >> 2)]);
    return;
  }
  i -= 1638400;
  if (i < 589824) {                    // wB2
    int p = i / 2304, kcol = i - p * 2304;
    int kt = kcol >> 6, slot = (kcol >> 3) & 7, j = kcol & 7;
    int c = ((kt & 3) << 6) + ((slot ^ (p & 7)) << 3) + j;
    wB2[i] = f2h(w2[(p * 256 + c) * 9 + (kt >> 2)]);
    return;
  }
  i -= 589824;
  if (i < 1536) {                      // bn params
    int grp = i >> 8, n = i & 255;
    const float* g  = (grp < 2) ? g1 : (grp < 4) ? g3 : g2;
    const float* bb = (grp < 2) ? b1 : (grp < 4) ? b3 : b2;
    const float* mm = (grp < 2) ? m1 : (grp < 4) ? m3 : m2;
    const float* vv = (grp < 2) ? v1 : (grp < 4) ? v3 : v2;
    float sc = g[n] / sqrtf(vv[n] + 1e-5f);
    bnp[i] = (grp & 1) ? (bb[n] - mm[n] * sc) : sc;
  }
}

// ---------------- pack x: NCHW f32 -> NHWC f16 border-2 ----------------
__global__ __launch_bounds__(256) void pack_x_kernel(const float* __restrict__ x,
                                                     u16* __restrict__ xp)
{
  __shared__ float trans[256][33];
  int b = blockIdx.x >> 5, y = blockIdx.x & 31;
  int t = threadIdx.x;
  int xi = t & 31, ch = t >> 5;
  const float* src = x + (b * 256 * 1024) + y * 32 + xi;
#pragma unroll 4
  for (int c8 = 0; c8 < 32; ++c8) {
    int c = c8 * 8 + ch;
    trans[c][xi] = src[c * 1024];
  }
  __syncthreads();
  u16* dstrow = xp + ((b * 36 + y + 2) * 36 + 2) * 256 + t;
#pragma unroll 4
  for (int xx = 0; xx < 32; ++xx)
    dstrow[xx * 256] = f2h(trans[t][xx]);
}

// ---------------- implicit-GEMM 3x3 conv ----------------
// XCD-aware swizzle: (phys&7)*per + (phys>>3) -> contiguous m-range per XCD.
template <int BN, int NBX, int WPAD, int EPI>
__global__ __launch_bounds__(256) void conv3x3_kernel(
    const u16* __restrict__ img, const u16* __restrict__ wB,
    const float* __restrict__ p0, const float* __restrict__ p1,
    const float* __restrict__ xorig, void* __restrict__ dst)
{
  constexpr int K = 2304;
  constexpr int NI = BN / 32;
  constexpr int BQ = BN / 32;
  constexpr int BRW = BN / 4;
  constexpr int BRD = (WPAD - 34) / 2;
  constexpr int PER = (NBX * 256) / 8;

  const int t = threadIdx.x;
  const int wave = t >> 6, lane = t & 63;
  const int lin = blockIdx.y * NBX + blockIdx.x;
  const int swz = (lin & 7) * PER + (lin >> 3);
  const int mBlk = (swz / NBX) * 128;
  const int nBlk = (swz % NBX) * BN;
  const int wm = wave >> 1, wn = wave & 1;

  __shared__ u16 Alds[128 * 64];
  __shared__ u16 Blds[BN * 64];

  int arow[4];
  {
    const int r0 = wave * 32 + (lane >> 3);
    const int chunk = (lane & 7) ^ (lane >> 3);   // XOR-swizzled source chunk
#pragma unroll
    for (int q = 0; q < 4; ++q) {
      int m = mBlk + r0 + q * 8;
      int b = m >> 10, y = (m >> 5) & 31, x = m & 31;
      arow[q] = ((b * WPAD + y + BRD) * WPAD + (x + BRD)) * 256 + chunk * 8;
    }
  }
  int brow[BQ];
  {
    const int r0 = nBlk + wave * BRW + (lane >> 3);
#pragma unroll
    for (int q = 0; q < BQ; ++q)
      brow[q] = (r0 + q * 8) * K + (lane & 7) * 8;
  }

  floatx4 acc[4][NI] = {};
  u16* adst = &Alds[wave * 32 * 64];
  u16* bdst = &Blds[wave * BRW * 64];

  for (int kt = 0; kt < 36; ++kt) {
    const int tap = kt >> 2, c0 = (kt & 3) << 6;
    const int kh = tap / 3, kw = tap - kh * 3;
    const int koff = (kh * WPAD + kw) * 256 + c0;
#pragma unroll
    for (int q = 0; q < 4; ++q)
      gload16(img + (arow[q] + koff), adst + q * 512);
#pragma unroll
    for (int q = 0; q < BQ; ++q)
      gload16(wB + (brow[q] + kt * 64), bdst + q * 512);
    __syncthreads();
#pragma unroll
    for (int kk = 0; kk < 2; ++kk) {
      const int sx = ((kk * 4 + (lane >> 4)) ^ (lane & 7)) << 3;
      half8 af[4], bfr[NI];
#pragma unroll
      for (int mi = 0; mi < 4; ++mi)
        af[mi] = *(const half8*)&Alds[(wm * 64 + mi * 16 + (lane & 15)) * 64 + sx];
#pragma unroll
      for (int ni = 0; ni < NI; ++ni)
        bfr[ni] = *(const half8*)&Blds[(wn * (BN / 2) + ni * 16 + (lane & 15)) * 64 + sx];
#pragma unroll
      for (int mi = 0; mi < 4; ++mi)
#pragma unroll
        for (int ni = 0; ni < NI; ++ni)
          acc[mi][ni] = __builtin_amdgcn_mfma_f32_16x16x32_f16(af[mi], bfr[ni], acc[mi][ni], 0, 0, 0);
    }
    __syncthreads();
  }

#pragma unroll
  for (int ni = 0; ni < NI; ++ni) {
    const int n = nBlk + wn * (BN / 2) + ni * 16 + (lane & 15);
    float sc = 0.f, bi = 0.f;
    if constexpr (EPI == 0 || EPI == 2) { sc = p0[n]; bi = p1[n]; }
    else { sc = (n < 50) ? p0[n] : 0.f; }
#pragma unroll
    for (int mi = 0; mi < 4; ++mi) {
      const int mb = mBlk + wm * 64 + mi * 16 + ((lane >> 4) << 2);
      if constexpr (EPI == 0) {
        u16* ym = (u16*)dst;
#pragma unroll
        for (int r = 0; r < 4; ++r) {
          int m = mb + r;
          int b = m >> 10, yy = (m >> 5) & 31, xx = m & 31;
          float v = fmaxf(acc[mi][ni][r] * sc + bi, 0.f);
          ym[((b * 34 + yy + 1) * 34 + (xx + 1)) * 256 + n] = f2h(v);
        }
      } else if constexpr (EPI == 1) {
        float* ob = (float*)dst;
#pragma unroll
        for (int r = 0; r < 4; ++r)
          ob[(mb + r) * 64 + n] = acc[mi][ni][r] + sc;
      } else {
        int b = mb >> 10, s = mb & 1023;
        const float* xr = xorig + ((b * 256 + n) << 10) + s;
        float* orow = (float*)dst + ((b * 256 + n) << 10) + s;
        floatx4 xv = *(const floatx4*)xr;
        floatx4 res;
#pragma unroll
        for (int r = 0; r < 4; ++r)
          res[r] = fmaxf(acc[mi][ni][r] * sc + bi + xv[r], 0.f);
        *(floatx4*)orow = res;
      }
    }
  }
}

// ---------------- deformable conv ----------------
struct Geo { float w00, w01, w10, w11; int base; };

__device__ __forceinline__ Geo mkgeo(int soh, int sow, int ti, int tj, float2 ov) {
  float py = (float)(soh - 2 + ti) + ov.x;
  float px = (float)(sow - 2 + tj) + ov.y;
  // zero-outside bilinear == clamp into [-1,32] vs border-2 zero-padded image
  py = fminf(32.f, fmaxf(-1.f, py));
  px = fminf(32.f, fmaxf(-1.f, px));
  float fy = floorf(py), fx = floorf(px);
  float wy1 = py - fy, wx1 = px - fx;
  float wy0 = 1.f - wy1, wx0 = 1.f - wx1;
  Geo g;
  g.w00 = wy0 * wx0; g.w01 = wy0 * wx1; g.w10 = wy1 * wx0; g.w11 = wy1 * wx1;
  g.base = (((int)fy + 2) * 36 + ((int)fx + 2)) * 256;
  return g;
}

// M=64 tile, N=256 split across 8 waves (32 cols each, acc[4][2]).
// 512-thread blocks, grid 512 -> 2 blocks = 16 waves/CU (double R5's TLP;
// R7 showed the binding constraint is wave-level overlap across barrier
// groups, not L2 BW). Loop = R5-proven: corners-first, blend, store, barrier,
// MFMA, barrier. 8 lanes share a sample row (8 ch each, 128B-coalesced);
// corner regs per thread shrink 32->16 VGPRs; launch_bounds(512,4) caps regs.
__global__ __launch_bounds__(512, 4) void deform_kernel(
    const u16* __restrict__ xp, const u16* __restrict__ wB,
    const float* __restrict__ offb,
    const float* __restrict__ sc3, const float* __restrict__ bi3,
    u16* __restrict__ ymid)
{
  constexpr int K = 6400;
  const int t = threadIdx.x;
  const int wave = t >> 6, lane = t & 63;
  const int phys = blockIdx.x;
  const int mBlk = ((phys & 7) * 64 + (phys >> 3)) * 64;   // XCD-contiguous

  __shared__ u16 Alds[64 * 64];    // 8 KB
  __shared__ u16 Blds[256 * 64];   // 32 KB

  const int srow = t >> 3, scg = t & 7;       // 8 lanes share a row
  const int sm = mBlk + srow;
  const int sb = sm >> 10, soh = (sm >> 5) & 31, sow = sm & 31;
  const u16* ximg = xp + sb * (36 * 36 * 256) + scg * 8;
  const float2* offrow = (const float2*)(offb + sm * 64);

  // B: each wave stages its own 32 rows (private -> no cross-wave dep)
  const int brow = (wave * 32 + (lane >> 3)) * K + (lane & 7) * 8;
  u16* bdst = &Blds[wave * 32 * 64];

  floatx4 acc[4][2] = {};

  for (int tap = 0; tap < 25; ++tap) {
    const int ti = tap / 5, tj = tap - ti * 5;
    const Geo g = mkgeo(soh, sow, ti, tj, offrow[tap]);
#pragma unroll
    for (int cc = 0; cc < 4; ++cc) {
      const int kt = tap * 4 + cc;
      // corner loads first (blend waits only these in the vmcnt queue)
      const u16* pb = ximg + g.base + cc * 64;
      half8 c00 = *(const half8*)(pb);
      half8 c01 = *(const half8*)(pb + 256);
      half8 c10 = *(const half8*)(pb + 9216);
      half8 c11 = *(const half8*)(pb + 9472);
      // B staging (drained by the barrier, overlaps the blend)
#pragma unroll
      for (int q = 0; q < 4; ++q)
        gload16(wB + (brow + q * 8 * K + kt * 64), bdst + q * 512);
      {
        _Float16 h00 = (_Float16)g.w00, h01 = (_Float16)g.w01;
        _Float16 h10 = (_Float16)g.w10, h11 = (_Float16)g.w11;
        half8 r = c00 * h00 + c01 * h01 + c10 * h10 + c11 * h11;
        const int slot = scg ^ (srow & 7);
        *(half8*)&Alds[srow * 64 + slot * 8] = r;
      }
      __syncthreads();
#pragma unroll
      for (int kk = 0; kk < 2; ++kk) {
        const int sx = ((kk * 4 + (lane >> 4)) ^ (lane & 7)) << 3;
        half8 af[4], bfr[2];
#pragma unroll
        for (int mi = 0; mi < 4; ++mi)
          af[mi] = *(const half8*)&Alds[(mi * 16 + (lane & 15)) * 64 + sx];
#pragma unroll
        for (int ni = 0; ni < 2; ++ni)
          bfr[ni] = *(const half8*)&Blds[(wave * 32 + ni * 16 + (lane & 15)) * 64 + sx];
#pragma unroll
        for (int mi = 0; mi < 4; ++mi)
#pragma unroll
          for (int ni = 0; ni < 2; ++ni)
            acc[mi][ni] = __builtin_amdgcn_mfma_f32_16x16x32_f16(af[mi], bfr[ni], acc[mi][ni], 0, 0, 0);
      }
      __syncthreads();
    }
  }

#pragma unroll
  for (int ni = 0; ni < 2; ++ni) {
    const int n = wave * 32 + ni * 16 + (lane & 15);
    float sc = sc3[n], bi = bi3[n];
#pragma unroll
    for (int mi = 0; mi < 4; ++mi) {
      const int mb = mBlk + mi * 16 + ((lane >> 4) << 2);
#pragma unroll
      for (int r = 0; r < 4; ++r) {
        int m = mb + r;
        int b = m >> 10, yy = (m >> 5) & 31, xx = m & 31;
        int idx = ((b * 34 + yy + 1) * 34 + (xx + 1)) * 256 + n;
        float v = fmaxf(acc[mi][ni][r] * sc + bi, 0.f) + h2f(ymid[idx]);
        ymid[idx] = f2h(v);
      }
    }
  }
}

// ---------------- launch ----------------
extern "C" void kernel_launch(void* const* d_in, const int* in_sizes, int n_in,
                              void* d_out, int out_size, void* d_ws, size_t ws_size,
                              hipStream_t stream)
{
  const float* x    = (const float*)d_in[0];
  const float* w1   = (const float*)d_in[1];
  const float* woff = (const float*)d_in[2];
  const float* boff = (const float*)d_in[3];
  const float* w3   = (const float*)d_in[4];
  const float* w2   = (const float*)d_in[5];
  const float* g1 = (const float*)d_in[6],  *b1 = (const float*)d_in[7];
  const float* m1 = (const float*)d_in[8],  *v1 = (const float*)d_in[9];
  const float* g3 = (const float*)d_in[10], *b3 = (const float*)d_in[11];
  const float* m3 = (const float*)d_in[12], *v3 = (const float*)d_in[13];
  const float* g2 = (const float*)d_in[14], *b2 = (const float*)d_in[15];
  const float* m2 = (const float*)d_in[16], *v2 = (const float*)d_in[17];

  char* ws = (char*)d_ws;
  u16*   xp   = (u16*)(ws + OFF_XP);
  u16*   ymid = (u16*)(ws + OFF_YMID);
  float* offb = (float*)(ws + OFF_OFFB);
  u16*   wB1  = (u16*)(ws + OFF_WB1);
  u16*   wBo  = (u16*)(ws + OFF_WBO);
  u16*   wB3  = (u16*)(ws + OFF_WB3);
  u16*   wB2  = (u16*)(ws + OFF_WB2);
  float* bnp  = (float*)(ws + OFF_BNP);

  zero_kernel<<<9808, 256, 0, stream>>>((uintx4*)ws, 2510848);
  prep_kernel<<<11590, 256, 0, stream>>>(w1, woff, w3, w2,
                                         g1, b1, m1, v1, g3, b3, m3, v3,
                                         g2, b2, m2, v2,
                                         wB1, wBo, wB3, wB2, bnp);
  pack_x_kernel<<<1024, 256, 0, stream>>>(x, xp);
  conv3x3_kernel<64, 1, 36, 1><<<dim3(1, 256), 256, 0, stream>>>(
      xp, wBo, boff, nullptr, nullptr, (void*)offb);
  conv3x3_kernel<128, 2, 36, 0><<<dim3(2, 256), 256, 0, stream>>>(
      xp, wB1, bnp + 0, bnp + 256, nullptr, (void*)ymid);
  deform_kernel<<<512, 512, 0, stream>>>(xp, wB3, offb, bnp + 512, bnp + 768, ymid);
  conv3x3_kernel<128, 2, 34, 2><<<dim3(2, 256), 256, 0, stream>>>(
      ymid, wB2, bnp + 1024, bnp + 1280, x, d_out);
}

// Round 9
// 413.325 us; speedup vs baseline: 1.0786x; 1.0288x over previous
//
#include <hip/hip_runtime.h>

typedef unsigned short u16;
typedef unsigned int u32;
typedef __attribute__((ext_vector_type(8))) _Float16 half8;
typedef __attribute__((ext_vector_type(4))) float floatx4;
typedef __attribute__((ext_vector_type(4))) u32 uintx4;

// ---------------- helpers ----------------
__device__ __forceinline__ u16 f2h(float f) {
  union { _Float16 h; u16 u; } v; v.h = (_Float16)f; return v.u;
}
__device__ __forceinline__ float h2f(u16 u) {
  union { u16 u; _Float16 h; } v; v.u = u; return (float)v.h;
}

typedef __attribute__((address_space(1))) const void* as1cv;
typedef __attribute__((address_space(3))) void* as3v;
__device__ __forceinline__ void gload16(const void* g, void* l) {
  __builtin_amdgcn_global_load_lds((as1cv)g, (as3v)l, 16, 0, 0);
}

// ---------------- ws layout (bytes) ----------------
// Weights now packed in MFMA-FRAGMENT order:
//   [kt][nt][kk][lane][8]  (chunk = (kt*NTW+nt)*2+kk is one 1KB wave-load)
//   n = nt*16 + (lane&15), k = kk*32 + (lane>>4)*8 + j, c = (kt&3)*64 + k
static constexpr size_t OFF_XP   = 0;         // [32][36][36][256] f16
static constexpr size_t OFF_YMID = 21233664;  // [32][34][34][256] f16
static constexpr size_t OFF_OFFB = 40173568;  // [32768][64] f32
static constexpr size_t OFF_WB1  = 48562176;  // 36*16*2*64*8 f16 frag-order
static constexpr size_t OFF_WBO  = 49741824;  // 36*4*2*64*8
static constexpr size_t OFF_WB3  = 50036736;  // 100*16*2*64*8
static constexpr size_t OFF_WB2  = 53313536;  // 36*16*2*64*8
static constexpr size_t OFF_BNP  = 54493184;  // [6][256] f32

// ---------------- zero fill ----------------
__global__ __launch_bounds__(256) void zero_kernel(uintx4* __restrict__ p, int n) {
  int i = blockIdx.x * 256 + threadIdx.x;
  if (i < n) { uintx4 z = {0u, 0u, 0u, 0u}; p[i] = z; }
}

// ---------------- pack weights (fragment-order) + bn params ----------------
__global__ __launch_bounds__(256) void prep_kernel(
    const float* __restrict__ w1, const float* __restrict__ woff,
    const float* __restrict__ w3, const float* __restrict__ w2,
    const float* __restrict__ g1, const float* __restrict__ b1,
    const float* __restrict__ m1, const float* __restrict__ v1,
    const float* __restrict__ g3, const float* __restrict__ b3,
    const float* __restrict__ m3, const float* __restrict__ v3,
    const float* __restrict__ g2, const float* __restrict__ b2,
    const float* __restrict__ m2, const float* __restrict__ v2,
    u16* __restrict__ wB1, u16* __restrict__ wBo,
    u16* __restrict__ wB3, u16* __restrict__ wB2,
    float* __restrict__ bnp)
{
  int i = blockIdx.x * 256 + threadIdx.x;
  if (i < 589824) {                    // wB1f [kt=36][nt=16][kk=2][lane][j]
    int j = i & 7, lane = (i >> 3) & 63, kk = (i >> 9) & 1;
    int nt = (i >> 10) & 15, kt = i >> 14;
    int n = nt * 16 + (lane & 15);
    int c = ((kt & 3) << 6) + kk * 32 + ((lane >> 4) << 3) + j;
    wB1[i] = f2h(w1[(n * 256 + c) * 9 + (kt >> 2)]);
    return;
  }
  i -= 589824;
  if (i < 147456) {                    // wBof [kt=36][nt=4][kk=2][lane][j]
    int j = i & 7, lane = (i >> 3) & 63, kk = (i >> 9) & 1;
    int nt = (i >> 10) & 3, kt = i >> 12;
    int n = nt * 16 + (lane & 15);
    int c = ((kt & 3) << 6) + kk * 32 + ((lane >> 4) << 3) + j;
    wBo[i] = (n < 50) ? f2h(woff[(n * 256 + c) * 9 + (kt >> 2)]) : (u16)0;
    return;
  }
  i -= 147456;
  if (i < 1638400) {                   // wB3f [kt=100][nt=16][kk=2][lane][j]
    int j = i & 7, lane = (i >> 3) & 63, kk = (i >> 9) & 1;
    int nt = (i >> 10) & 15, kt = i >> 14;
    int n = nt * 16 + (lane & 15);
    int c = ((kt & 3) << 6) + kk * 32 + ((lane >> 4) << 3) + j;
    wB3[i] = f2h(w3[(n * 256 + c) * 25 + (kt >> 2)]);
    return;
  }
  i -= 1638400;
  if (i < 589824) {                    // wB2f
    int j = i & 7, lane = (i >> 3) & 63, kk = (i >> 9) & 1;
    int nt = (i >> 10) & 15, kt = i >> 14;
    int n = nt * 16 + (lane & 15);
    int c = ((kt & 3) << 6) + kk * 32 + ((lane >> 4) << 3) + j;
    wB2[i] = f2h(w2[(n * 256 + c) * 9 + (kt >> 2)]);
    return;
  }
  i -= 589824;
  if (i < 1536) {                      // bn params
    int grp = i >> 8, n = i & 255;
    const float* g  = (grp < 2) ? g1 : (grp < 4) ? g3 : g2;
    const float* bb = (grp < 2) ? b1 : (grp < 4) ? b3 : b2;
    const float* mm = (grp < 2) ? m1 : (grp < 4) ? m3 : m2;
    const float* vv = (grp < 2) ? v1 : (grp < 4) ? v3 : v2;
    float sc = g[n] / sqrtf(vv[n] + 1e-5f);
    bnp[i] = (grp & 1) ? (bb[n] - mm[n] * sc) : sc;
  }
}

// ---------------- pack x: NCHW f32 -> NHWC f16 border-2 ----------------
__global__ __launch_bounds__(256) void pack_x_kernel(const float* __restrict__ x,
                                                     u16* __restrict__ xp)
{
  __shared__ float trans[256][33];
  int b = blockIdx.x >> 5, y = blockIdx.x & 31;
  int t = threadIdx.x;
  int xi = t & 31, ch = t >> 5;
  const float* src = x + (b * 256 * 1024) + y * 32 + xi;
#pragma unroll 4
  for (int c8 = 0; c8 < 32; ++c8) {
    int c = c8 * 8 + ch;
    trans[c][xi] = src[c * 1024];
  }
  __syncthreads();
  u16* dstrow = xp + ((b * 36 + y + 2) * 36 + 2) * 256 + t;
#pragma unroll 4
  for (int xx = 0; xx < 32; ++xx)
    dstrow[xx * 256] = f2h(trans[t][xx]);
}

// ---------------- implicit-GEMM 3x3 conv ----------------
// A via global_load_lds (XOR-swizzled); B fragments loaded DIRECTLY from
// global in fragment order (wave-private, L1/L2-hot) — no B LDS at all.
template <int BN, int NBX, int WPAD, int EPI, int NTW>
__global__ __launch_bounds__(256) void conv3x3_kernel(
    const u16* __restrict__ img, const u16* __restrict__ wB,
    const float* __restrict__ p0, const float* __restrict__ p1,
    const float* __restrict__ xorig, void* __restrict__ dst)
{
  constexpr int NI = BN / 32;
  constexpr int BRD = (WPAD - 34) / 2;
  constexpr int PER = (NBX * 256) / 8;

  const int t = threadIdx.x;
  const int wave = t >> 6, lane = t & 63;
  const int lin = blockIdx.y * NBX + blockIdx.x;
  const int swz = (lin & 7) * PER + (lin >> 3);
  const int mBlk = (swz / NBX) * 128;
  const int nBlk = (swz % NBX) * BN;
  const int wm = wave >> 1, wn = wave & 1;

  __shared__ u16 Alds[128 * 64];   // 16 KB

  int arow[4];
  {
    const int r0 = wave * 32 + (lane >> 3);
    const int chunk = (lane & 7) ^ (lane >> 3);   // XOR-swizzled source chunk
#pragma unroll
    for (int q = 0; q < 4; ++q) {
      int m = mBlk + r0 + q * 8;
      int b = m >> 10, y = (m >> 5) & 31, x = m & 31;
      arow[q] = ((b * WPAD + y + BRD) * WPAD + (x + BRD)) * 256 + chunk * 8;
    }
  }
  const int ntB = (nBlk >> 4) + wn * (BN / 32);   // this wave's first n-tile
  const u16* wfrag = wB + lane * 8;

  floatx4 acc[4][NI] = {};
  u16* adst = &Alds[wave * 32 * 64];

  for (int kt = 0; kt < 36; ++kt) {
    const int tap = kt >> 2, c0 = (kt & 3) << 6;
    const int kh = tap / 3, kw = tap - kh * 3;
    const int koff = (kh * WPAD + kw) * 256 + c0;
#pragma unroll
    for (int q = 0; q < 4; ++q)
      gload16(img + (arow[q] + koff), adst + q * 512);
    // direct B fragment loads (drained by the barrier)
    half8 bfr[NI][2];
#pragma unroll
    for (int ni = 0; ni < NI; ++ni)
#pragma unroll
      for (int kk = 0; kk < 2; ++kk)
        bfr[ni][kk] = *(const half8*)(wfrag + (((kt * NTW + ntB + ni) * 2 + kk) << 9));
    __syncthreads();
#pragma unroll
    for (int kk = 0; kk < 2; ++kk) {
      const int sx = ((kk * 4 + (lane >> 4)) ^ (lane & 7)) << 3;
      half8 af[4];
#pragma unroll
      for (int mi = 0; mi < 4; ++mi)
        af[mi] = *(const half8*)&Alds[(wm * 64 + mi * 16 + (lane & 15)) * 64 + sx];
#pragma unroll
      for (int mi = 0; mi < 4; ++mi)
#pragma unroll
        for (int ni = 0; ni < NI; ++ni)
          acc[mi][ni] = __builtin_amdgcn_mfma_f32_16x16x32_f16(af[mi], bfr[ni][kk], acc[mi][ni], 0, 0, 0);
    }
    __syncthreads();
  }

#pragma unroll
  for (int ni = 0; ni < NI; ++ni) {
    const int n = nBlk + wn * (BN / 2) + ni * 16 + (lane & 15);
    float sc = 0.f, bi = 0.f;
    if constexpr (EPI == 0 || EPI == 2) { sc = p0[n]; bi = p1[n]; }
    else { sc = (n < 50) ? p0[n] : 0.f; }
#pragma unroll
    for (int mi = 0; mi < 4; ++mi) {
      const int mb = mBlk + wm * 64 + mi * 16 + ((lane >> 4) << 2);
      if constexpr (EPI == 0) {
        u16* ym = (u16*)dst;
#pragma unroll
        for (int r = 0; r < 4; ++r) {
          int m = mb + r;
          int b = m >> 10, yy = (m >> 5) & 31, xx = m & 31;
          float v = fmaxf(acc[mi][ni][r] * sc + bi, 0.f);
          ym[((b * 34 + yy + 1) * 34 + (xx + 1)) * 256 + n] = f2h(v);
        }
      } else if constexpr (EPI == 1) {
        float* ob = (float*)dst;
#pragma unroll
        for (int r = 0; r < 4; ++r)
          ob[(mb + r) * 64 + n] = acc[mi][ni][r] + sc;
      } else {
        int b = mb >> 10, s = mb & 1023;
        const float* xr = xorig + ((b * 256 + n) << 10) + s;
        float* orow = (float*)dst + ((b * 256 + n) << 10) + s;
        floatx4 xv = *(const floatx4*)xr;
        floatx4 res;
#pragma unroll
        for (int r = 0; r < 4; ++r)
          res[r] = fmaxf(acc[mi][ni][r] * sc + bi + xv[r], 0.f);
        *(floatx4*)orow = res;
      }
    }
  }
}

// ---------------- deformable conv ----------------
struct Geo { float w00, w01, w10, w11; int base; };

__device__ __forceinline__ Geo mkgeo(int soh, int sow, int ti, int tj, float2 ov) {
  float py = (float)(soh - 2 + ti) + ov.x;
  float px = (float)(sow - 2 + tj) + ov.y;
  // zero-outside bilinear == clamp into [-1,32] vs border-2 zero-padded image
  py = fminf(32.f, fmaxf(-1.f, py));
  px = fminf(32.f, fmaxf(-1.f, px));
  float fy = floorf(py), fx = floorf(px);
  float wy1 = py - fy, wx1 = px - fx;
  float wy0 = 1.f - wy1, wx0 = 1.f - wx1;
  Geo g;
  g.w00 = wy0 * wx0; g.w01 = wy0 * wx1; g.w10 = wy1 * wx0; g.w11 = wy1 * wx1;
  g.base = (((int)fy + 2) * 36 + ((int)fx + 2)) * 256;
  return g;
}

struct Corners { half8 v00[2], v01[2], v10[2], v11[2]; };

__device__ __forceinline__ Corners loadC(const u16* __restrict__ pb) {
  Corners c;
#pragma unroll
  for (int gg = 0; gg < 2; ++gg) {
    c.v00[gg] = *(const half8*)(pb + gg * 8);
    c.v01[gg] = *(const half8*)(pb + gg * 8 + 256);
    c.v10[gg] = *(const half8*)(pb + gg * 8 + 9216);
    c.v11[gg] = *(const half8*)(pb + gg * 8 + 9472);
  }
  return c;
}

__device__ __forceinline__ void blendStore(const Corners& c, const Geo& g,
                                           int scg, int srow, u16* __restrict__ adst) {
  _Float16 h00 = (_Float16)g.w00, h01 = (_Float16)g.w01;
  _Float16 h10 = (_Float16)g.w10, h11 = (_Float16)g.w11;
#pragma unroll
  for (int gg = 0; gg < 2; ++gg) {
    half8 r = c.v00[gg] * h00 + c.v01[gg] * h01 + c.v10[gg] * h10 + c.v11[gg] * h11;
    int slot = (scg * 2 + gg) ^ (srow & 7);
    *(half8*)&adst[srow * 64 + slot * 8] = r;
  }
}

// M=64, N=256, 4 waves (R5 shape: least A-read redundancy). B fragments come
// straight from global (fragment-packed wB3f, L1-resident 32KB/phase slice);
// LDS holds only the 8KB A tile. Loop = R5: corners -> B frags -> blend ->
// store -> barrier -> MFMA -> barrier.
__global__ __launch_bounds__(256) void deform_kernel(
    const u16* __restrict__ xp, const u16* __restrict__ wBf,
    const float* __restrict__ offb,
    const float* __restrict__ sc3, const float* __restrict__ bi3,
    u16* __restrict__ ymid)
{
  const int t = threadIdx.x;
  const int wave = t >> 6, lane = t & 63;
  const int phys = blockIdx.x;
  const int mBlk = ((phys & 7) * 64 + (phys >> 3)) * 64;   // XCD-contiguous

  __shared__ u16 Alds[64 * 64];    // 8 KB

  const int srow = t >> 2, scg = t & 3;       // 4 lanes share a row: coalesced corners
  const int sm = mBlk + srow;
  const int sb = sm >> 10, soh = (sm >> 5) & 31, sow = sm & 31;
  const u16* ximg = xp + sb * (36 * 36 * 256) + scg * 16;
  const float2* offrow = (const float2*)(offb + sm * 64);

  const u16* wfrag = wBf + lane * 8;

  floatx4 acc[4][4] = {};

  for (int tap = 0; tap < 25; ++tap) {
    const int ti = tap / 5, tj = tap - ti * 5;
    const Geo g = mkgeo(soh, sow, ti, tj, offrow[tap]);
#pragma unroll
    for (int cc = 0; cc < 4; ++cc) {
      const int kt = tap * 4 + cc;
      // corner loads first (blend waits only these; B frags stay outstanding)
      Corners c = loadC(ximg + g.base + cc * 64);
      // direct B fragment loads (same addr on every block -> L1/L2 hot)
      half8 bfr[4][2];
#pragma unroll
      for (int ni = 0; ni < 4; ++ni)
#pragma unroll
        for (int kk = 0; kk < 2; ++kk)
          bfr[ni][kk] = *(const half8*)(wfrag + (((kt * 16 + wave * 4 + ni) * 2 + kk) << 9));
      blendStore(c, g, scg, srow, Alds);
      __syncthreads();
#pragma unroll
      for (int kk = 0; kk < 2; ++kk) {
        const int sx = ((kk * 4 + (lane >> 4)) ^ (lane & 7)) << 3;
        half8 af[4];
#pragma unroll
        for (int mi = 0; mi < 4; ++mi)
          af[mi] = *(const half8*)&Alds[(mi * 16 + (lane & 15)) * 64 + sx];
#pragma unroll
        for (int mi = 0; mi < 4; ++mi)
#pragma unroll
          for (int ni = 0; ni < 4; ++ni)
            acc[mi][ni] = __builtin_amdgcn_mfma_f32_16x16x32_f16(af[mi], bfr[ni][kk], acc[mi][ni], 0, 0, 0);
      }
      __syncthreads();
    }
  }

#pragma unroll
  for (int ni = 0; ni < 4; ++ni) {
    const int n = wave * 64 + ni * 16 + (lane & 15);
    float sc = sc3[n], bi = bi3[n];
#pragma unroll
    for (int mi = 0; mi < 4; ++mi) {
      const int mb = mBlk + mi * 16 + ((lane >> 4) << 2);
#pragma unroll
      for (int r = 0; r < 4; ++r) {
        int m = mb + r;
        int b = m >> 10, yy = (m >> 5) & 31, xx = m & 31;
        int idx = ((b * 34 + yy + 1) * 34 + (xx + 1)) * 256 + n;
        float v = fmaxf(acc[mi][ni][r] * sc + bi, 0.f) + h2f(ymid[idx]);
        ymid[idx] = f2h(v);
      }
    }
  }
}

// ---------------- launch ----------------
extern "C" void kernel_launch(void* const* d_in, const int* in_sizes, int n_in,
                              void* d_out, int out_size, void* d_ws, size_t ws_size,
                              hipStream_t stream)
{
  const float* x    = (const float*)d_in[0];
  const float* w1   = (const float*)d_in[1];
  const float* woff = (const float*)d_in[2];
  const float* boff = (const float*)d_in[3];
  const float* w3   = (const float*)d_in[4];
  const float* w2   = (const float*)d_in[5];
  const float* g1 = (const float*)d_in[6],  *b1 = (const float*)d_in[7];
  const float* m1 = (const float*)d_in[8],  *v1 = (const float*)d_in[9];
  const float* g3 = (const float*)d_in[10], *b3 = (const float*)d_in[11];
  const float* m3 = (const float*)d_in[12], *v3 = (const float*)d_in[13];
  const float* g2 = (const float*)d_in[14], *b2 = (const float*)d_in[15];
  const float* m2 = (const float*)d_in[16], *v2 = (const float*)d_in[17];

  char* ws = (char*)d_ws;
  u16*   xp   = (u16*)(ws + OFF_XP);
  u16*   ymid = (u16*)(ws + OFF_YMID);
  float* offb = (float*)(ws + OFF_OFFB);
  u16*   wB1  = (u16*)(ws + OFF_WB1);
  u16*   wBo  = (u16*)(ws + OFF_WBO);
  u16*   wB3  = (u16*)(ws + OFF_WB3);
  u16*   wB2  = (u16*)(ws + OFF_WB2);
  float* bnp  = (float*)(ws + OFF_BNP);

  zero_kernel<<<9808, 256, 0, stream>>>((uintx4*)ws, 2510848);
  prep_kernel<<<11590, 256, 0, stream>>>(w1, woff, w3, w2,
                                         g1, b1, m1, v1, g3, b3, m3, v3,
                                         g2, b2, m2, v2,
                                         wB1, wBo, wB3, wB2, bnp);
  pack_x_kernel<<<1024, 256, 0, stream>>>(x, xp);
  conv3x3_kernel<64, 1, 36, 1, 4><<<dim3(1, 256), 256, 0, stream>>>(
      xp, wBo, boff, nullptr, nullptr, (void*)offb);
  conv3x3_kernel<128, 2, 36, 0, 16><<<dim3(2, 256), 256, 0, stream>>>(
      xp, wB1, bnp + 0, bnp + 256, nullptr, (void*)ymid);
  deform_kernel<<<512, 256, 0, stream>>>(xp, wB3, offb, bnp + 512, bnp + 768, ymid);
  conv3x3_kernel<128, 2, 34, 2, 16><<<dim3(2, 256), 256, 0, stream>>>(
      ymid, wB2, bnp + 1024, bnp + 1280, x, d_out);
}